// Round 1
// baseline (101.276 us; speedup 1.0000x reference)
//
#include <hip/hip_runtime.h>
#include <math.h>

#define NODE_DIM 128
#define HIDDEN   64
#define NN       2048

typedef float v4f __attribute__((ext_vector_type(4)));

// ---------------------------------------------------------------------------
// Prep: per node row r:
//   h  = nf[r] @ W_enc + b_enc          (128 -> 64)
//   A[r]  = h @ W1[:64]                 (64 -> 64)
//   BB[r] = h @ W1[64:] + b1            (64 -> 64, b1 folded in)
// 4 rows per 256-thread block; one 64-lane wave per row.
// ---------------------------------------------------------------------------
__global__ __launch_bounds__(256) void prep_kernel(
    const float* __restrict__ nf, const float* __restrict__ W_enc,
    const float* __restrict__ b_enc, const float* __restrict__ W1,
    const float* __restrict__ b1, float* __restrict__ A, float* __restrict__ BB)
{
    __shared__ float nf_s[4][NODE_DIM];
    __shared__ float h_s[4][HIDDEN];
    const int tid = threadIdx.x;
    const int rg  = tid >> 6;   // row group within block (0..3)
    const int t   = tid & 63;   // output column / lane
    const int r   = blockIdx.x * 4 + rg;

    // stage node-feature row: 128 floats per row, float2 per lane (coalesced)
    ((float2*)nf_s[rg])[t] = ((const float2*)(nf + (size_t)r * NODE_DIM))[t];
    __syncthreads();

    float acc = b_enc[t];
    #pragma unroll 8
    for (int k = 0; k < NODE_DIM; ++k)
        acc = fmaf(nf_s[rg][k], W_enc[k * HIDDEN + t], acc);  // coalesced across t
    h_s[rg][t] = acc;
    __syncthreads();

    float aacc = 0.0f;
    float bacc = b1[t];
    #pragma unroll 8
    for (int k = 0; k < HIDDEN; ++k) {
        const float hv = h_s[rg][k];                           // LDS broadcast
        aacc = fmaf(hv, W1[k * HIDDEN + t], aacc);
        bacc = fmaf(hv, W1[(HIDDEN + k) * HIDDEN + t], bacc);
    }
    A[(size_t)r * HIDDEN + t]  = aacc;
    BB[(size_t)r * HIDDEN + t] = bacc;
}

// ---------------------------------------------------------------------------
// Pairwise: T[i][j] = sigmoid( sum_h relu(A[i,h] + BB[j,h]) * W2[h] + b2 ),
// diagonal zeroed. One 64x64 output tile per block, 4x4 micro-tile per thread.
// LDS: aL row-major [i][h], bT transposed [h][j]; stride 68 floats keeps
// float4 alignment (272 B) and spreads banks (all compute reads <=2-way).
// ---------------------------------------------------------------------------
__global__ __launch_bounds__(256) void pair_kernel(
    const float* __restrict__ A, const float* __restrict__ BB,
    const float* __restrict__ W2, const float* __restrict__ b2,
    float* __restrict__ out)
{
    __shared__ float aL[64][68];   // [i][h]
    __shared__ float bT[64][68];   // [h][j]
    __shared__ float w2s[HIDDEN];

    const int tid = threadIdx.x;
    const int i0  = blockIdx.y * 64;
    const int j0  = blockIdx.x * 64;

    // Stage tiles. Each 64-row x 64-col tile is a contiguous 16 KB global
    // region -> perfectly coalesced float4 loads (4 per thread per tile).
    const float4* ga = (const float4*)(A  + (size_t)i0 * HIDDEN);
    const float4* gb = (const float4*)(BB + (size_t)j0 * HIDDEN);
    #pragma unroll
    for (int k = 0; k < 4; ++k) {
        const int idx = tid + k * 256;   // float4 index 0..1023
        const int e   = idx * 4;
        const int row = e >> 6;          // node index within tile
        const int col = e & 63;          // h index (multiple of 4)
        const float4 va = ga[idx];
        const float4 vb = gb[idx];
        *(float4*)&aL[row][col] = va;    // straight copy, 16B aligned
        bT[col + 0][row] = vb.x;         // transpose (one-time scalar writes)
        bT[col + 1][row] = vb.y;
        bT[col + 2][row] = vb.z;
        bT[col + 3][row] = vb.w;
    }
    if (tid < HIDDEN) w2s[tid] = W2[tid];
    __syncthreads();

    const int ty = tid >> 4;   // 0..3  : i micro-row group
    const int tx = tid & 15;   // 0..15 : j micro-col group

    float acc[4][4] = {{0.0f}};

    #pragma unroll 4
    for (int h = 0; h < HIDDEN; h += 4) {
        const v4f w = *(const v4f*)&w2s[h];          // broadcast, free
        v4f av[4], bv[4];
        #pragma unroll
        for (int ii = 0; ii < 4; ++ii)
            av[ii] = *(const v4f*)&aL[ty * 4 + ii][h];   // 2-way max
        #pragma unroll
        for (int hh = 0; hh < 4; ++hh)
            bv[hh] = *(const v4f*)&bT[h + hh][tx * 4];   // 2-way max
        #pragma unroll
        for (int ii = 0; ii < 4; ++ii) {
            #pragma unroll
            for (int jj = 0; jj < 4; ++jj) {
                float s = acc[ii][jj];
                #pragma unroll
                for (int hh = 0; hh < 4; ++hh)
                    s = fmaf(fmaxf(av[ii][hh] + bv[hh][jj], 0.0f), w[hh], s);
                acc[ii][jj] = s;
            }
        }
    }

    const float bias2 = b2[0];
    #pragma unroll
    for (int ii = 0; ii < 4; ++ii) {
        const int i = i0 + ty * 4 + ii;
        v4f o;
        #pragma unroll
        for (int jj = 0; jj < 4; ++jj) {
            const int j = j0 + tx * 4 + jj;
            const float x  = acc[ii][jj] + bias2;
            const float sg = 1.0f / (1.0f + __expf(-x));
            o[jj] = (i == j) ? 0.0f : sg;
        }
        *(v4f*)&out[(size_t)i * NN + (j0 + tx * 4)] = o;
    }
}

extern "C" void kernel_launch(void* const* d_in, const int* in_sizes, int n_in,
                              void* d_out, int out_size, void* d_ws, size_t ws_size,
                              hipStream_t stream) {
    const float* nf    = (const float*)d_in[0];
    const float* W_enc = (const float*)d_in[1];
    const float* b_enc = (const float*)d_in[2];
    const float* W1    = (const float*)d_in[3];
    const float* b1    = (const float*)d_in[4];
    const float* W2    = (const float*)d_in[5];
    const float* b2    = (const float*)d_in[6];
    float* out = (float*)d_out;

    float* A  = (float*)d_ws;                 // 2048*64 floats
    float* BB = A + (size_t)NN * HIDDEN;      // 2048*64 floats (1 MB total)

    prep_kernel<<<NN / 4, 256, 0, stream>>>(nf, W_enc, b_enc, W1, b1, A, BB);
    pair_kernel<<<dim3(32, 32), 256, 0, stream>>>(A, BB, W2, b2, out);
}

// Round 5
// 100.744 us; speedup vs baseline: 1.0053x; 1.0053x over previous
//
#include <hip/hip_runtime.h>
#include <math.h>

#define NODE_DIM 128
#define HIDDEN   64
#define NN       2048
#define LSTR     68   // floats per LDS row: 64 data + 4 pad (272 B, 16B-aligned)

typedef float v2f __attribute__((ext_vector_type(2)));
typedef float v4f __attribute__((ext_vector_type(4)));

// ---------------------------------------------------------------------------
// Prep — VERBATIM from the PASSING R1 kernel:
//   h = nf[r] @ W_enc + b_enc
//   A[r]  = h @ W1[:64]
//   BB[r] = h @ W1[64:] + b1          (b1 folded)
// fp32 outputs. One 64-lane wave per row, 4 rows per block.
// ---------------------------------------------------------------------------
__global__ __launch_bounds__(256) void prep_kernel(
    const float* __restrict__ nf, const float* __restrict__ W_enc,
    const float* __restrict__ b_enc, const float* __restrict__ W1,
    const float* __restrict__ b1, float* __restrict__ A, float* __restrict__ BB)
{
    __shared__ float nf_s[4][NODE_DIM];
    __shared__ float h_s[4][HIDDEN];
    const int tid = threadIdx.x;
    const int rg  = tid >> 6;
    const int t   = tid & 63;
    const int r   = blockIdx.x * 4 + rg;

    ((float2*)nf_s[rg])[t] = ((const float2*)(nf + (size_t)r * NODE_DIM))[t];
    __syncthreads();

    float acc = b_enc[t];
    #pragma unroll 8
    for (int k = 0; k < NODE_DIM; ++k)
        acc = fmaf(nf_s[rg][k], W_enc[k * HIDDEN + t], acc);
    h_s[rg][t] = acc;
    __syncthreads();

    float aacc = 0.0f;
    float bacc = b1[t];
    #pragma unroll 8
    for (int k = 0; k < HIDDEN; ++k) {
        const float hv = h_s[rg][k];
        aacc = fmaf(hv, W1[k * HIDDEN + t], aacc);
        bacc = fmaf(hv, W1[(HIDDEN + k) * HIDDEN + t], bacc);
    }
    A[(size_t)r * HIDDEN + t]  = aacc;
    BB[(size_t)r * HIDDEN + t] = bacc;
}

// ---------------------------------------------------------------------------
// Pairwise: T[i][j] = sigmoid( b2 + sum_h relu(A[i,h]+BB[j,h]) * W2[h] ).
// Pure fp32. Tile 128i x 128j per block (grid 16x16 = 256 = 1 block/CU),
// 256 threads, 8x8 micro-tile, i = i0+ty+16*ii, j = j0+tx+16*jj.
// Packed over h: float2 ops (lo=even h, hi=odd h), float2 accumulator per
// output, horizontal fold in epilogue -> compiler can emit v_pk_*_f32
// (2x fp32 rate); if it doesn't, this is exactly R1's scalar math (correct).
// LDS stride 68: A-reads 4 rows/wave -> bank-quads {0,4,8,12} conflict-free;
// B-reads 16 rows -> 2-way (free). __launch_bounds__(256,2) caps VGPR<=256.
// ---------------------------------------------------------------------------
__global__ __launch_bounds__(256, 2) void pair_kernel(
    const float* __restrict__ A, const float* __restrict__ BB,
    const float* __restrict__ W2, const float* __restrict__ b2,
    float* __restrict__ out)
{
    __shared__ __align__(16) float aL[128 * LSTR];   // 34.8 KB
    __shared__ __align__(16) float bL[128 * LSTR];   // 34.8 KB

    const int tid = threadIdx.x;
    const int i0  = blockIdx.y * 128;
    const int j0  = blockIdx.x * 128;

    // ---- stage: each tile = 128 rows x 64 floats = 2048 float4s ----
    const v4f* gA = (const v4f*)(A  + (size_t)i0 * HIDDEN);
    const v4f* gB = (const v4f*)(BB + (size_t)j0 * HIDDEN);
    #pragma unroll
    for (int k = 0; k < 8; ++k) {
        const int idx = tid + k * 256;   // 0..2047
        const int row = idx >> 4;        // 16 float4 per row
        const int c   = idx & 15;
        *(v4f*)&aL[row * LSTR + c * 4] = gA[idx];
        *(v4f*)&bL[row * LSTR + c * 4] = gB[idx];
    }
    __syncthreads();

    const int ty = tid >> 4;   // 0..15 : i = i0 + ty + 16*ii
    const int tx = tid & 15;   // 0..15 : j = j0 + tx + 16*jj

    v2f acc[8][8];
    #pragma unroll
    for (int ii = 0; ii < 8; ++ii)
        #pragma unroll
        for (int jj = 0; jj < 8; ++jj)
            acc[ii][jj] = (v2f){0.0f, 0.0f};

    const v2f vz = (v2f){0.0f, 0.0f};

    #pragma unroll 2
    for (int c = 0; c < 16; ++c) {       // 4 h per chunk = 2 h-pairs
        v4f av[8], bv[8];
        #pragma unroll
        for (int ii = 0; ii < 8; ++ii)
            av[ii] = *(const v4f*)&aL[(ty + 16 * ii) * LSTR + c * 4];
        #pragma unroll
        for (int jj = 0; jj < 8; ++jj)
            bv[jj] = *(const v4f*)&bL[(tx + 16 * jj) * LSTR + c * 4];

        const v2f w0 = (v2f){W2[c * 4 + 0], W2[c * 4 + 1]};   // uniform -> SGPR
        const v2f w1 = (v2f){W2[c * 4 + 2], W2[c * 4 + 3]};

        #pragma unroll
        for (int ii = 0; ii < 8; ++ii) {
            const v2f a0 = __builtin_shufflevector(av[ii], av[ii], 0, 1);
            const v2f a1 = __builtin_shufflevector(av[ii], av[ii], 2, 3);
            #pragma unroll
            for (int jj = 0; jj < 8; ++jj) {
                const v2f b0 = __builtin_shufflevector(bv[jj], bv[jj], 0, 1);
                const v2f b1v = __builtin_shufflevector(bv[jj], bv[jj], 2, 3);
                v2f t0 = a0 + b0;
                t0 = __builtin_elementwise_max(t0, vz);
                acc[ii][jj] += t0 * w0;
                v2f t1 = a1 + b1v;
                t1 = __builtin_elementwise_max(t1, vz);
                acc[ii][jj] += t1 * w1;
            }
        }
    }

    // ---- epilogue: fold pair-lanes, +b2, sigmoid, zero diagonal ----
    const float b2v = b2[0];
    #pragma unroll
    for (int ii = 0; ii < 8; ++ii) {
        const int i = i0 + ty + 16 * ii;
        #pragma unroll
        for (int jj = 0; jj < 8; ++jj) {
            const int j = j0 + tx + 16 * jj;
            const float lg = acc[ii][jj][0] + acc[ii][jj][1] + b2v;
            const float sg = 1.0f / (1.0f + __expf(-lg));
            out[(size_t)i * NN + j] = (i == j) ? 0.0f : sg;
        }
    }
}

extern "C" void kernel_launch(void* const* d_in, const int* in_sizes, int n_in,
                              void* d_out, int out_size, void* d_ws, size_t ws_size,
                              hipStream_t stream) {
    const float* nf    = (const float*)d_in[0];
    const float* W_enc = (const float*)d_in[1];
    const float* b_enc = (const float*)d_in[2];
    const float* W1    = (const float*)d_in[3];
    const float* b1    = (const float*)d_in[4];
    const float* W2    = (const float*)d_in[5];
    const float* b2    = (const float*)d_in[6];
    float* out = (float*)d_out;

    float* A  = (float*)d_ws;                 // 2048*64 fp32 (512 KB)
    float* BB = A + (size_t)NN * HIDDEN;      // 512 KB

    // block sizes match __launch_bounds__ exactly (R4's failure mode).
    prep_kernel<<<NN / 4, 256, 0, stream>>>(nf, W_enc, b_enc, W1, b1, A, BB);
    pair_kernel<<<dim3(NN / 128, NN / 128), 256, 0, stream>>>(
        A, BB, W2, b2, out);
}